// Round 1
// baseline (1599.283 us; speedup 1.0000x reference)
//
#include <hip/hip_runtime.h>

// GIN: 5 conv layers (CSR-gather aggregation + per-node MLP) + pool + readout.
// fp32 throughout. Round 1: correctness-first, structured for iteration.

constexpr int N   = 100000;
constexpr int E   = 1600000;
constexpr int DIN = 128;
constexpr int H   = 64;
constexpr int OUT = 16;
constexpr int G   = 512;

constexpr int NB_NODES    = (N + 255) / 256;       // 391
constexpr int NB_EDGES    = (E + 255) / 256;       // 6250
constexpr int NB_WAVENODE = (N * 64 + 255) / 256;  // 25000 (wave per node)

__global__ void k_zero_int(int* __restrict__ p, int n) {
  int i = blockIdx.x * 256 + threadIdx.x;
  if (i < n) p[i] = 0;
}

__global__ void k_hist(const int* __restrict__ dst, int* __restrict__ deg) {
  int e = blockIdx.x * 256 + threadIdx.x;
  if (e < E) atomicAdd(&deg[dst[e]], 1);
}

// Exclusive scan of deg[N] -> rowptr, per-256 block, block totals to bsums.
__global__ void k_scan_block(const int* __restrict__ deg, int* __restrict__ rowptr,
                             int* __restrict__ bsums) {
  __shared__ int s[256];
  int i = blockIdx.x * 256 + threadIdx.x;
  int v = (i < N) ? deg[i] : 0;
  s[threadIdx.x] = v;
  __syncthreads();
  for (int off = 1; off < 256; off <<= 1) {
    int t = 0;
    if ((int)threadIdx.x >= off) t = s[threadIdx.x - off];
    __syncthreads();
    if ((int)threadIdx.x >= off) s[threadIdx.x] += t;
    __syncthreads();
  }
  if (i < N) rowptr[i] = s[threadIdx.x] - v;  // exclusive within block
  if (threadIdx.x == 255) bsums[blockIdx.x] = s[255];
}

__global__ void k_scan_sums(int* __restrict__ bsums, int nb) {
  __shared__ int s[512];
  int t = threadIdx.x;
  int v = (t < nb) ? bsums[t] : 0;
  s[t] = v;
  __syncthreads();
  for (int off = 1; off < 512; off <<= 1) {
    int u = 0;
    if (t >= off) u = s[t - off];
    __syncthreads();
    if (t >= off) s[t] += u;
    __syncthreads();
  }
  if (t < nb) bsums[t] = s[t] - v;  // exclusive block offsets
}

__global__ void k_scan_add(int* __restrict__ rowptr, const int* __restrict__ bsums,
                           int* __restrict__ cursor) {
  int i = blockIdx.x * 256 + threadIdx.x;
  if (i < N) {
    int v = rowptr[i] + bsums[blockIdx.x];
    rowptr[i] = v;
    cursor[i] = v;
  }
  if (i == 0) rowptr[N] = E;
}

__global__ void k_fill(const int* __restrict__ src, const int* __restrict__ dst,
                       int* __restrict__ cursor, int* __restrict__ col) {
  int e = blockIdx.x * 256 + threadIdx.x;
  if (e < E) {
    int p = atomicAdd(&cursor[dst[e]], 1);
    col[p] = src[e];
  }
}

__global__ void k_transpose(const float* __restrict__ w, float* __restrict__ wt,
                            int rows, int cols) {
  int t = blockIdx.x * 256 + threadIdx.x;
  if (t < rows * cols) {
    int r = t / cols, c = t % cols;
    wt[c * rows + r] = w[t];
  }
}

// out[n][:] = h[n][:] + sum_{e in row n} h[col[e]][:]   (wave per node, lane per feat)
__global__ void k_aggregate64(const float* __restrict__ h, const int* __restrict__ rowptr,
                              const int* __restrict__ col, float* __restrict__ out) {
  int w = (blockIdx.x * 256 + threadIdx.x) >> 6;
  int lane = threadIdx.x & 63;
  if (w >= N) return;
  int r0 = rowptr[w], r1 = rowptr[w + 1];
  float acc = h[(size_t)w * 64 + lane];
  for (int k = r0; k < r1; ++k) {
    int s = col[k];  // wave-uniform
    acc += h[(size_t)s * 64 + lane];
  }
  out[(size_t)w * 64 + lane] = acc;
}

__global__ void k_aggregate128(const float* __restrict__ h, const int* __restrict__ rowptr,
                               const int* __restrict__ col, float* __restrict__ out) {
  int w = (blockIdx.x * 256 + threadIdx.x) >> 6;
  int lane = threadIdx.x & 63;
  if (w >= N) return;
  int r0 = rowptr[w], r1 = rowptr[w + 1];
  const float2* h2 = (const float2*)h;
  float2 acc = h2[(size_t)w * 64 + lane];
  for (int k = r0; k < r1; ++k) {
    int s = col[k];
    float2 v = h2[(size_t)s * 64 + lane];
    acc.x += v.x;
    acc.y += v.y;
  }
  ((float2*)out)[(size_t)w * 64 + lane] = acc;
}

// out = relu( relu(z @ w1 + b1) @ w2 + b2 ), thread per node, 64 accs in VGPRs.
// w1 is [D][H] row-major (as given); w2t is [H][H] pre-transposed (row j2 = col j2 of w2).
template <int D>
__global__ void k_mlp(const float* __restrict__ z, const float* __restrict__ w1,
                      const float* __restrict__ b1, const float* __restrict__ w2t,
                      const float* __restrict__ b2, float* __restrict__ out) {
  int n = blockIdx.x * 256 + threadIdx.x;
  if (n >= N) return;
  float acc[H];
#pragma unroll
  for (int j = 0; j < H; ++j) acc[j] = b1[j];
  const float* zr = z + (size_t)n * D;
#pragma unroll 4
  for (int d = 0; d < D; ++d) {
    float zd = zr[d];
#pragma unroll
    for (int j = 0; j < H; ++j) acc[j] += zd * w1[d * H + j];  // uniform addr -> s_load
  }
#pragma unroll
  for (int j = 0; j < H; ++j) acc[j] = fmaxf(acc[j], 0.f);
  float* orow = out + (size_t)n * H;
  for (int j2 = 0; j2 < H; ++j2) {
    const float* wr = w2t + j2 * H;
    float s = b2[j2];
#pragma unroll
    for (int d = 0; d < H; ++d) s += acc[d] * wr[d];
    orow[j2] = fmaxf(s, 0.f);
  }
}

__global__ void k_pool(const float* __restrict__ h, const int* __restrict__ batch,
                       float* __restrict__ g) {
  int w = (blockIdx.x * 256 + threadIdx.x) >> 6;
  int lane = threadIdx.x & 63;
  if (w >= N) return;
  int b = batch[w];
  __hip_atomic_fetch_add(&g[(size_t)b * 64 + lane], h[(size_t)w * 64 + lane],
                         __ATOMIC_RELAXED, __HIP_MEMORY_SCOPE_AGENT);
}

// out[n] = relu(g[n] @ mw1 + mb1) @ mw2 + mb2   (no outer relu)
__global__ void k_readout(const float* __restrict__ g, const float* __restrict__ mw1,
                          const float* __restrict__ mb1, const float* __restrict__ mw2t,
                          const float* __restrict__ mb2, float* __restrict__ out) {
  int n = blockIdx.x * 256 + threadIdx.x;
  if (n >= G) return;
  float acc[H];
#pragma unroll
  for (int j = 0; j < H; ++j) acc[j] = mb1[j];
  const float* gr = g + (size_t)n * H;
#pragma unroll 4
  for (int d = 0; d < H; ++d) {
    float zd = gr[d];
#pragma unroll
    for (int j = 0; j < H; ++j) acc[j] += zd * mw1[d * H + j];
  }
#pragma unroll
  for (int j = 0; j < H; ++j) acc[j] = fmaxf(acc[j], 0.f);
#pragma unroll
  for (int o = 0; o < OUT; ++o) {
    float s = mb2[o];
#pragma unroll
    for (int d = 0; d < H; ++d) s += acc[d] * mw2t[o * H + d];
    out[(size_t)n * OUT + o] = s;
  }
}

extern "C" void kernel_launch(void* const* d_in, const int* in_sizes, int n_in,
                              void* d_out, int out_size, void* d_ws, size_t ws_size,
                              hipStream_t stream) {
  const float* x     = (const float*)d_in[0];
  const int*   ei    = (const int*)d_in[1];
  const int*   batch = (const int*)d_in[2];
  const float* w1_0  = (const float*)d_in[3];
  const float* b1_0  = (const float*)d_in[4];
  const float* w2_0  = (const float*)d_in[5];
  const float* b2_0  = (const float*)d_in[6];
  const float* w1_r  = (const float*)d_in[7];
  const float* b1_r  = (const float*)d_in[8];
  const float* w2_r  = (const float*)d_in[9];
  const float* b2_r  = (const float*)d_in[10];
  const float* mw1   = (const float*)d_in[11];
  const float* mb1   = (const float*)d_in[12];
  const float* mw2   = (const float*)d_in[13];
  const float* mb2   = (const float*)d_in[14];
  float* out = (float*)d_out;

  const int* src = ei;
  const int* dst = ei + E;

  char* ws = (char*)d_ws;
  size_t off = 0;
  auto alloc = [&](size_t bytes) -> void* {
    void* p = ws + off;
    off = (off + bytes + 255) & ~(size_t)255;
    return p;
  };
  float* z128 = (float*)alloc((size_t)N * DIN * 4);  // layer-0 aggregated input
  float* abuf = (float*)alloc((size_t)N * H * 4);    // aggregated (layers 1-4)
  float* hbuf = (float*)alloc((size_t)N * H * 4);    // hidden state h
  int* rowptr = (int*)alloc((size_t)(N + 1) * 4);
  int* cursor = (int*)alloc((size_t)N * 4);          // also deg during build
  int* col    = (int*)alloc((size_t)E * 4);
  int* bsums  = (int*)alloc(512 * 4);
  float* gbuf = (float*)alloc((size_t)G * H * 4);
  float* w2t0 = (float*)alloc((size_t)H * H * 4);
  float* w2tr = (float*)alloc((size_t)4 * H * H * 4);
  float* mw2t = (float*)alloc((size_t)H * OUT * 4);

  // ---- CSR build (deg lives in `cursor` until scan_add rewrites it) ----
  k_zero_int<<<NB_NODES, 256, 0, stream>>>(cursor, N);
  k_hist<<<NB_EDGES, 256, 0, stream>>>(dst, cursor);
  k_scan_block<<<NB_NODES, 256, 0, stream>>>(cursor, rowptr, bsums);
  k_scan_sums<<<1, 512, 0, stream>>>(bsums, NB_NODES);
  k_scan_add<<<NB_NODES, 256, 0, stream>>>(rowptr, bsums, cursor);
  k_fill<<<NB_EDGES, 256, 0, stream>>>(src, dst, cursor, col);

  // ---- weight transposes for GEMM2 row-contiguous access ----
  k_transpose<<<16, 256, 0, stream>>>(w2_0, w2t0, H, H);
  for (int i = 0; i < 4; ++i)
    k_transpose<<<16, 256, 0, stream>>>(w2_r + i * H * H, w2tr + i * H * H, H, H);
  k_transpose<<<4, 256, 0, stream>>>(mw2, mw2t, H, OUT);

  hipMemsetAsync(gbuf, 0, (size_t)G * H * 4, stream);

  // ---- layer 0 (DIN=128) ----
  k_aggregate128<<<NB_WAVENODE, 256, 0, stream>>>(x, rowptr, col, z128);
  k_mlp<DIN><<<NB_NODES, 256, 0, stream>>>(z128, w1_0, b1_0, w2t0, b2_0, hbuf);

  // ---- layers 1-4 (H=64) ----
  for (int i = 0; i < 4; ++i) {
    k_aggregate64<<<NB_WAVENODE, 256, 0, stream>>>(hbuf, rowptr, col, abuf);
    k_mlp<H><<<NB_NODES, 256, 0, stream>>>(abuf, w1_r + i * H * H, b1_r + i * H,
                                           w2tr + i * H * H, b2_r + i * H, hbuf);
  }

  // ---- pool + readout ----
  k_pool<<<NB_WAVENODE, 256, 0, stream>>>(hbuf, batch, gbuf);
  k_readout<<<2, 256, 0, stream>>>(gbuf, mw1, mb1, mw2t, mb2, out);
}

// Round 2
// 1138.294 us; speedup vs baseline: 1.4050x; 1.4050x over previous
//
#include <hip/hip_runtime.h>

// GIN on MI355X. Round 2:
//  - linearity trick: aggregate y = h@w1 (64-wide) instead of h (128-wide at layer 0)
//  - bf16 storage for the gathered feature matrix (halves gather bytes)
//  - agg inner loop unrolled x4 (4 independent accumulators -> 4 outstanding loads)
//  - fused GEMM2(i)+ReLU+GEMM1(i+1) thread-per-node kernels, no weight transposes

constexpr int N   = 100000;
constexpr int E   = 1600000;
constexpr int DIN = 128;
constexpr int H   = 64;
constexpr int OUT = 16;
constexpr int G   = 512;

constexpr int NB_NODES    = (N + 255) / 256;       // 391
constexpr int NB_EDGES    = (E + 255) / 256;       // 6250
constexpr int NB_WAVENODE = (N * 64 + 255) / 256;  // 25000 (wave per node)
constexpr int NB_T64      = (N + 63) / 64;         // 1563 (thread per node, 64/blk)

__device__ __forceinline__ float bf2f(unsigned short u) {
  union { unsigned int i; float f; } v;
  v.i = ((unsigned int)u) << 16;
  return v.f;
}
__device__ __forceinline__ unsigned short f2bf(float f) {
  union { float f; unsigned int i; } v;
  v.f = f;
  unsigned int r = v.i + 0x7fff + ((v.i >> 16) & 1);  // RNE
  return (unsigned short)(r >> 16);
}

// ---------------- CSR build ----------------
__global__ void k_zero_int(int* __restrict__ p, int n) {
  int i = blockIdx.x * 256 + threadIdx.x;
  if (i < n) p[i] = 0;
}

__global__ void k_hist(const int* __restrict__ dst, int* __restrict__ deg) {
  int e = blockIdx.x * 256 + threadIdx.x;
  if (e < E) atomicAdd(&deg[dst[e]], 1);
}

__global__ void k_scan_block(const int* __restrict__ deg, int* __restrict__ rowptr,
                             int* __restrict__ bsums) {
  __shared__ int s[256];
  int i = blockIdx.x * 256 + threadIdx.x;
  int v = (i < N) ? deg[i] : 0;
  s[threadIdx.x] = v;
  __syncthreads();
  for (int off = 1; off < 256; off <<= 1) {
    int t = 0;
    if ((int)threadIdx.x >= off) t = s[threadIdx.x - off];
    __syncthreads();
    if ((int)threadIdx.x >= off) s[threadIdx.x] += t;
    __syncthreads();
  }
  if (i < N) rowptr[i] = s[threadIdx.x] - v;
  if (threadIdx.x == 255) bsums[blockIdx.x] = s[255];
}

__global__ void k_scan_sums(int* __restrict__ bsums, int nb) {
  __shared__ int s[512];
  int t = threadIdx.x;
  int v = (t < nb) ? bsums[t] : 0;
  s[t] = v;
  __syncthreads();
  for (int off = 1; off < 512; off <<= 1) {
    int u = 0;
    if (t >= off) u = s[t - off];
    __syncthreads();
    if (t >= off) s[t] += u;
    __syncthreads();
  }
  if (t < nb) bsums[t] = s[t] - v;
}

__global__ void k_scan_add(int* __restrict__ rowptr, const int* __restrict__ bsums,
                           int* __restrict__ cursor) {
  int i = blockIdx.x * 256 + threadIdx.x;
  if (i < N) {
    int v = rowptr[i] + bsums[blockIdx.x];
    rowptr[i] = v;
    cursor[i] = v;
  }
  if (i == 0) rowptr[N] = E;
}

__global__ void k_fill(const int* __restrict__ src, const int* __restrict__ dst,
                       int* __restrict__ cursor, int* __restrict__ col) {
  int e = blockIdx.x * 256 + threadIdx.x;
  if (e < E) {
    int p = atomicAdd(&cursor[dst[e]], 1);
    col[p] = src[e];
  }
}

// ---------------- y0 = x @ w1_0  (N x 128 -> N x 64, bf16 out) ----------------
__global__ void k_gemm_in(const float* __restrict__ x, const float* __restrict__ w1,
                          unsigned short* __restrict__ y) {
  int n = blockIdx.x * 64 + threadIdx.x;
  if (n >= N) return;
  float acc[H];
#pragma unroll
  for (int j = 0; j < H; ++j) acc[j] = 0.f;
  const float4* xr = (const float4*)(x + (size_t)n * DIN);
  for (int d4 = 0; d4 < DIN / 4; ++d4) {
    float4 v = xr[d4];
    const float* wr = w1 + d4 * 4 * H;
#pragma unroll
    for (int j = 0; j < H; ++j)
      acc[j] += v.x * wr[j] + v.y * wr[H + j] + v.z * wr[2 * H + j] + v.w * wr[3 * H + j];
  }
  unsigned int* yo = (unsigned int*)(y + (size_t)n * H);
#pragma unroll
  for (int j = 0; j < H; j += 2)
    yo[j / 2] = (unsigned int)f2bf(acc[j]) | ((unsigned int)f2bf(acc[j + 1]) << 16);
}

// ---- u = relu(y + A*y + b1), wave per node, lane per feature, unroll x4 ----
__global__ void k_agg(const unsigned short* __restrict__ y, const int* __restrict__ rowptr,
                      const int* __restrict__ col, const float* __restrict__ b1,
                      float* __restrict__ u) {
  int w = (blockIdx.x * 256 + threadIdx.x) >> 6;
  int lane = threadIdx.x & 63;
  if (w >= N) return;
  int r0 = rowptr[w], r1 = rowptr[w + 1];
  float a0 = bf2f(y[(size_t)w * H + lane]);
  float a1 = 0.f, a2 = 0.f, a3 = 0.f;
  int k = r0;
  for (; k + 4 <= r1; k += 4) {
    int c0 = col[k], c1 = col[k + 1], c2 = col[k + 2], c3 = col[k + 3];
    a0 += bf2f(y[(size_t)c0 * H + lane]);
    a1 += bf2f(y[(size_t)c1 * H + lane]);
    a2 += bf2f(y[(size_t)c2 * H + lane]);
    a3 += bf2f(y[(size_t)c3 * H + lane]);
  }
  for (; k < r1; ++k) a0 += bf2f(y[(size_t)col[k] * H + lane]);
  float r = (a0 + a1) + (a2 + a3) + b1[lane];
  u[(size_t)w * H + lane] = fmaxf(r, 0.f);
}

// ---- y_next = (relu(u @ w2 + b2)) @ w1next, bf16 out. Thread per node. ----
__global__ void k_fused(const float* __restrict__ u, const float* __restrict__ w2,
                        const float* __restrict__ b2, const float* __restrict__ w1n,
                        unsigned short* __restrict__ ynext) {
  int n = blockIdx.x * 64 + threadIdx.x;
  if (n >= N) return;
  float h[H];
#pragma unroll
  for (int j = 0; j < H; ++j) h[j] = b2[j];
  const float4* ur = (const float4*)(u + (size_t)n * H);
  for (int d4 = 0; d4 < H / 4; ++d4) {
    float4 v = ur[d4];
    const float* wr = w2 + d4 * 4 * H;
#pragma unroll
    for (int j = 0; j < H; ++j)
      h[j] += v.x * wr[j] + v.y * wr[H + j] + v.z * wr[2 * H + j] + v.w * wr[3 * H + j];
  }
#pragma unroll
  for (int j = 0; j < H; ++j) h[j] = fmaxf(h[j], 0.f);
  float a[H];
#pragma unroll
  for (int j = 0; j < H; ++j) a[j] = 0.f;
  for (int d = 0; d < H; ++d) {
    float hd = h[d];
    const float* wr = w1n + d * H;
#pragma unroll
    for (int j = 0; j < H; ++j) a[j] += hd * wr[j];
  }
  unsigned int* yo = (unsigned int*)(ynext + (size_t)n * H);
#pragma unroll
  for (int j = 0; j < H; j += 2)
    yo[j / 2] = (unsigned int)f2bf(a[j]) | ((unsigned int)f2bf(a[j + 1]) << 16);
}

// ---- h5 = relu(u @ w2 + b2), fp32 out (feeds pooling) ----
__global__ void k_last(const float* __restrict__ u, const float* __restrict__ w2,
                       const float* __restrict__ b2, float* __restrict__ h5) {
  int n = blockIdx.x * 64 + threadIdx.x;
  if (n >= N) return;
  float h[H];
#pragma unroll
  for (int j = 0; j < H; ++j) h[j] = b2[j];
  const float4* ur = (const float4*)(u + (size_t)n * H);
  for (int d4 = 0; d4 < H / 4; ++d4) {
    float4 v = ur[d4];
    const float* wr = w2 + d4 * 4 * H;
#pragma unroll
    for (int j = 0; j < H; ++j)
      h[j] += v.x * wr[j] + v.y * wr[H + j] + v.z * wr[2 * H + j] + v.w * wr[3 * H + j];
  }
  float4* ho = (float4*)(h5 + (size_t)n * H);
#pragma unroll
  for (int j = 0; j < H; j += 4)
    ho[j / 4] = make_float4(fmaxf(h[j], 0.f), fmaxf(h[j + 1], 0.f),
                            fmaxf(h[j + 2], 0.f), fmaxf(h[j + 3], 0.f));
}

__global__ void k_pool(const float* __restrict__ h, const int* __restrict__ batch,
                       float* __restrict__ g) {
  int w = (blockIdx.x * 256 + threadIdx.x) >> 6;
  int lane = threadIdx.x & 63;
  if (w >= N) return;
  int b = batch[w];
  __hip_atomic_fetch_add(&g[(size_t)b * H + lane], h[(size_t)w * H + lane],
                         __ATOMIC_RELAXED, __HIP_MEMORY_SCOPE_AGENT);
}

// out[n] = relu(g[n] @ mw1 + mb1) @ mw2 + mb2
__global__ void k_readout(const float* __restrict__ g, const float* __restrict__ mw1,
                          const float* __restrict__ mb1, const float* __restrict__ mw2,
                          const float* __restrict__ mb2, float* __restrict__ out) {
  int n = blockIdx.x * 64 + threadIdx.x;
  if (n >= G) return;
  float acc[H];
#pragma unroll
  for (int j = 0; j < H; ++j) acc[j] = mb1[j];
  const float* gr = g + (size_t)n * H;
  for (int d = 0; d < H; ++d) {
    float gd = gr[d];
    const float* wr = mw1 + d * H;
#pragma unroll
    for (int j = 0; j < H; ++j) acc[j] += gd * wr[j];
  }
#pragma unroll
  for (int j = 0; j < H; ++j) acc[j] = fmaxf(acc[j], 0.f);
  float o[OUT];
#pragma unroll
  for (int t = 0; t < OUT; ++t) o[t] = mb2[t];
  for (int d = 0; d < H; ++d) {
    float hd = acc[d];
    const float* wr = mw2 + d * OUT;
#pragma unroll
    for (int t = 0; t < OUT; ++t) o[t] += hd * wr[t];
  }
#pragma unroll
  for (int t = 0; t < OUT; ++t) out[(size_t)n * OUT + t] = o[t];
}

extern "C" void kernel_launch(void* const* d_in, const int* in_sizes, int n_in,
                              void* d_out, int out_size, void* d_ws, size_t ws_size,
                              hipStream_t stream) {
  const float* x     = (const float*)d_in[0];
  const int*   ei    = (const int*)d_in[1];
  const int*   batch = (const int*)d_in[2];
  const float* w1_0  = (const float*)d_in[3];
  const float* b1_0  = (const float*)d_in[4];
  const float* w2_0  = (const float*)d_in[5];
  const float* b2_0  = (const float*)d_in[6];
  const float* w1_r  = (const float*)d_in[7];
  const float* b1_r  = (const float*)d_in[8];
  const float* w2_r  = (const float*)d_in[9];
  const float* b2_r  = (const float*)d_in[10];
  const float* mw1   = (const float*)d_in[11];
  const float* mb1   = (const float*)d_in[12];
  const float* mw2   = (const float*)d_in[13];
  const float* mb2   = (const float*)d_in[14];
  float* out = (float*)d_out;

  const int* src = ei;
  const int* dst = ei + E;

  char* ws = (char*)d_ws;
  size_t off = 0;
  auto alloc = [&](size_t bytes) -> void* {
    void* p = ws + off;
    off = (off + bytes + 255) & ~(size_t)255;
    return p;
  };
  unsigned short* ybuf = (unsigned short*)alloc((size_t)N * H * 2);  // y = h@w1, bf16
  float* ubuf = (float*)alloc((size_t)N * H * 4);                    // relu(y + Ay + b1)
  float* h5   = (float*)alloc((size_t)N * H * 4);                    // final hidden
  int* rowptr = (int*)alloc((size_t)(N + 1) * 4);
  int* cursor = (int*)alloc((size_t)N * 4);
  int* col    = (int*)alloc((size_t)E * 4);
  int* bsums  = (int*)alloc(512 * 4);
  float* gbuf = (float*)alloc((size_t)G * H * 4);

  // ---- CSR build ----
  k_zero_int<<<NB_NODES, 256, 0, stream>>>(cursor, N);
  k_hist<<<NB_EDGES, 256, 0, stream>>>(dst, cursor);
  k_scan_block<<<NB_NODES, 256, 0, stream>>>(cursor, rowptr, bsums);
  k_scan_sums<<<1, 512, 0, stream>>>(bsums, NB_NODES);
  k_scan_add<<<NB_NODES, 256, 0, stream>>>(rowptr, bsums, cursor);
  k_fill<<<NB_EDGES, 256, 0, stream>>>(src, dst, cursor, col);

  hipMemsetAsync(gbuf, 0, (size_t)G * H * 4, stream);

  // ---- layer 0: y0 = x @ w1_0 (bf16), then per-layer agg + fused MLP ----
  k_gemm_in<<<NB_T64, 64, 0, stream>>>(x, w1_0, ybuf);

  k_agg<<<NB_WAVENODE, 256, 0, stream>>>(ybuf, rowptr, col, b1_0, ubuf);
  k_fused<<<NB_T64, 64, 0, stream>>>(ubuf, w2_0, b2_0, w1_r /* layer1 w1 */, ybuf);

  for (int i = 0; i < 3; ++i) {
    k_agg<<<NB_WAVENODE, 256, 0, stream>>>(ybuf, rowptr, col, b1_r + i * H, ubuf);
    k_fused<<<NB_T64, 64, 0, stream>>>(ubuf, w2_r + i * H * H, b2_r + i * H,
                                       w1_r + (i + 1) * H * H, ybuf);
  }

  // layer 4: agg, then plain GEMM2 -> h5 (fp32)
  k_agg<<<NB_WAVENODE, 256, 0, stream>>>(ybuf, rowptr, col, b1_r + 3 * H, ubuf);
  k_last<<<NB_T64, 64, 0, stream>>>(ubuf, w2_r + 3 * H * H, b2_r + 3 * H, h5);

  // ---- pool + readout ----
  k_pool<<<NB_WAVENODE, 256, 0, stream>>>(h5, batch, gbuf);
  k_readout<<<8, 64, 0, stream>>>(gbuf, mw1, mb1, mw2, mb2, out);
}

// Round 3
// 874.535 us; speedup vs baseline: 1.8287x; 1.3016x over previous
//
#include <hip/hip_runtime.h>

// GIN on MI355X. Round 3:
//  - MLP family rewritten as tiled block-GEMMs: 256 thr / 64 nodes per block,
//    padded-LDS node tile (conflict-free), wave-uniform 16-wide output group
//    (weights via scalar loads), LDS-staged coalesced stores.
//  - agg / CSR build / pool unchanged from round 2.

constexpr int N   = 100000;
constexpr int E   = 1600000;
constexpr int DIN = 128;
constexpr int H   = 64;
constexpr int OUT = 16;
constexpr int G   = 512;

constexpr int NB_NODES    = (N + 255) / 256;       // 391
constexpr int NB_EDGES    = (E + 255) / 256;       // 6250
constexpr int NB_WAVENODE = (N * 64 + 255) / 256;  // 25000 (wave per node)
constexpr int NB_TILE64   = (N + 63) / 64;         // 1563 (64-node tiles)

__device__ __forceinline__ float bf2f(unsigned short u) {
  union { unsigned int i; float f; } v;
  v.i = ((unsigned int)u) << 16;
  return v.f;
}
__device__ __forceinline__ unsigned int f2bf(float f) {
  union { float f; unsigned int i; } v;
  v.f = f;
  unsigned int r = v.i + 0x7fff + ((v.i >> 16) & 1);  // RNE
  return r >> 16;
}

// ---------------- CSR build ----------------
__global__ void k_zero_int(int* __restrict__ p, int n) {
  int i = blockIdx.x * 256 + threadIdx.x;
  if (i < n) p[i] = 0;
}

__global__ void k_hist(const int* __restrict__ dst, int* __restrict__ deg) {
  int e = blockIdx.x * 256 + threadIdx.x;
  if (e < E) atomicAdd(&deg[dst[e]], 1);
}

__global__ void k_scan_block(const int* __restrict__ deg, int* __restrict__ rowptr,
                             int* __restrict__ bsums) {
  __shared__ int s[256];
  int i = blockIdx.x * 256 + threadIdx.x;
  int v = (i < N) ? deg[i] : 0;
  s[threadIdx.x] = v;
  __syncthreads();
  for (int off = 1; off < 256; off <<= 1) {
    int t = 0;
    if ((int)threadIdx.x >= off) t = s[threadIdx.x - off];
    __syncthreads();
    if ((int)threadIdx.x >= off) s[threadIdx.x] += t;
    __syncthreads();
  }
  if (i < N) rowptr[i] = s[threadIdx.x] - v;
  if (threadIdx.x == 255) bsums[blockIdx.x] = s[255];
}

__global__ void k_scan_sums(int* __restrict__ bsums, int nb) {
  __shared__ int s[512];
  int t = threadIdx.x;
  int v = (t < nb) ? bsums[t] : 0;
  s[t] = v;
  __syncthreads();
  for (int off = 1; off < 512; off <<= 1) {
    int u = 0;
    if (t >= off) u = s[t - off];
    __syncthreads();
    if (t >= off) s[t] += u;
    __syncthreads();
  }
  if (t < nb) bsums[t] = s[t] - v;
}

__global__ void k_scan_add(int* __restrict__ rowptr, const int* __restrict__ bsums,
                           int* __restrict__ cursor) {
  int i = blockIdx.x * 256 + threadIdx.x;
  if (i < N) {
    int v = rowptr[i] + bsums[blockIdx.x];
    rowptr[i] = v;
    cursor[i] = v;
  }
  if (i == 0) rowptr[N] = E;
}

__global__ void k_fill(const int* __restrict__ src, const int* __restrict__ dst,
                       int* __restrict__ cursor, int* __restrict__ col) {
  int e = blockIdx.x * 256 + threadIdx.x;
  if (e < E) {
    int p = atomicAdd(&cursor[dst[e]], 1);
    col[p] = src[e];
  }
}

// ---- y0 = x @ w1_0 (N x 128 -> N x 64, bf16 out). 64-node tile per block. ----
__global__ __launch_bounds__(256, 4) void k_gemm_in(const float* __restrict__ x,
                                                    const float* __restrict__ w1,
                                                    unsigned short* __restrict__ y) {
  __shared__ float sx[64 * 129];
  int t = threadIdx.x;
  int nb = blockIdx.x * 64;
  int rows = min(64, N - nb);
  // stage x tile: 64 rows x 128 f, coalesced float4 loads, padded scalar LDS stores
#pragma unroll
  for (int it = 0; it < 8; ++it) {
    int idx4 = it * 256 + t;           // float4 index, 0..2047
    int r = idx4 >> 5, d4 = idx4 & 31;
    if (r < rows) {
      float4 v = ((const float4*)(x + (size_t)(nb + r) * DIN))[d4];
      float* dl = &sx[r * 129 + d4 * 4];
      dl[0] = v.x; dl[1] = v.y; dl[2] = v.z; dl[3] = v.w;
    }
  }
  __syncthreads();
  int l = t & 63;
  int jg = __builtin_amdgcn_readfirstlane(t >> 6);  // wave-uniform output group
  float acc[16];
#pragma unroll
  for (int j = 0; j < 16; ++j) acc[j] = 0.f;
#pragma unroll 4
  for (int d = 0; d < DIN; ++d) {
    float v = sx[l * 129 + d];
    const float* wr = w1 + d * H + jg * 16;  // uniform -> s_load
#pragma unroll
    for (int j = 0; j < 16; ++j) acc[j] += v * wr[j];
  }
  __syncthreads();  // all sx reads done; reuse sx for bf16 staging
  unsigned int* so = (unsigned int*)sx;  // 64 rows x 32 uints, pad 33
#pragma unroll
  for (int k = 0; k < 8; ++k)
    so[l * 33 + jg * 8 + k] = f2bf(acc[2 * k]) | (f2bf(acc[2 * k + 1]) << 16);
  __syncthreads();
  unsigned int* yo = (unsigned int*)y;
#pragma unroll
  for (int it = 0; it < 2; ++it) {
    int m = it * 256 + t;  // 0..511 of 2048? no: 2 iters x 256 = 512... need 2048/256=8? rows*32 uints
    // 64 rows * 32 uints = 2048 -> 8 iterations
  }
  // (do it properly with 8 iterations)
#pragma unroll
  for (int it = 0; it < 8; ++it) {
    int m = it * 256 + t;
    int r = m >> 5, k = m & 31;
    if (r < rows) yo[(size_t)(nb + r) * 32 + k] = so[r * 33 + k];
  }
}

// ---- u = relu(y + A*y + b1), wave per node, lane per feature, unroll x4 ----
__global__ void k_agg(const unsigned short* __restrict__ y, const int* __restrict__ rowptr,
                      const int* __restrict__ col, const float* __restrict__ b1,
                      float* __restrict__ u) {
  int w = (blockIdx.x * 256 + threadIdx.x) >> 6;
  int lane = threadIdx.x & 63;
  if (w >= N) return;
  int r0 = rowptr[w], r1 = rowptr[w + 1];
  float a0 = bf2f(y[(size_t)w * H + lane]);
  float a1 = 0.f, a2 = 0.f, a3 = 0.f;
  int k = r0;
  for (; k + 4 <= r1; k += 4) {
    int c0 = col[k], c1 = col[k + 1], c2 = col[k + 2], c3 = col[k + 3];
    a0 += bf2f(y[(size_t)c0 * H + lane]);
    a1 += bf2f(y[(size_t)c1 * H + lane]);
    a2 += bf2f(y[(size_t)c2 * H + lane]);
    a3 += bf2f(y[(size_t)c3 * H + lane]);
  }
  for (; k < r1; ++k) a0 += bf2f(y[(size_t)col[k] * H + lane]);
  float r = (a0 + a1) + (a2 + a3) + b1[lane];
  u[(size_t)w * H + lane] = fmaxf(r, 0.f);
}

// ---- y_next = (relu(u @ w2 + b2)) @ w1next, bf16 out. 64-node tile. ----
__global__ __launch_bounds__(256, 4) void k_fused(const float* __restrict__ u,
                                                  const float* __restrict__ w2,
                                                  const float* __restrict__ b2,
                                                  const float* __restrict__ w1n,
                                                  unsigned short* __restrict__ ynext) {
  __shared__ float sa[64 * 65];
  __shared__ float sb[64 * 65];
  int t = threadIdx.x;
  int nb = blockIdx.x * 64;
  int rows = min(64, N - nb);
#pragma unroll
  for (int it = 0; it < 4; ++it) {
    int idx4 = it * 256 + t;           // float4 index, 0..1023
    int r = idx4 >> 4, d4 = idx4 & 15;
    if (r < rows) {
      float4 v = ((const float4*)(u + (size_t)(nb + r) * H))[d4];
      float* dl = &sa[r * 65 + d4 * 4];
      dl[0] = v.x; dl[1] = v.y; dl[2] = v.z; dl[3] = v.w;
    }
  }
  __syncthreads();
  int l = t & 63;
  int jg = __builtin_amdgcn_readfirstlane(t >> 6);
  float h[16];
#pragma unroll
  for (int j = 0; j < 16; ++j) h[j] = b2[jg * 16 + j];
#pragma unroll 4
  for (int d = 0; d < H; ++d) {
    float v = sa[l * 65 + d];
    const float* wr = w2 + d * H + jg * 16;
#pragma unroll
    for (int j = 0; j < 16; ++j) h[j] += v * wr[j];
  }
#pragma unroll
  for (int j = 0; j < 16; ++j) sb[l * 65 + jg * 16 + j] = fmaxf(h[j], 0.f);
  __syncthreads();  // sb complete; also guarantees all sa reads done
  float a[16];
#pragma unroll
  for (int j = 0; j < 16; ++j) a[j] = 0.f;
#pragma unroll 4
  for (int d = 0; d < H; ++d) {
    float v = sb[l * 65 + d];
    const float* wr = w1n + d * H + jg * 16;
#pragma unroll
    for (int j = 0; j < 16; ++j) a[j] += v * wr[j];
  }
  unsigned int* so = (unsigned int*)sa;  // safe: sa reads finished before 2nd barrier
#pragma unroll
  for (int k = 0; k < 8; ++k)
    so[l * 33 + jg * 8 + k] = f2bf(a[2 * k]) | (f2bf(a[2 * k + 1]) << 16);
  __syncthreads();
  unsigned int* yo = (unsigned int*)ynext;
#pragma unroll
  for (int it = 0; it < 8; ++it) {
    int m = it * 256 + t;
    int r = m >> 5, k = m & 31;
    if (r < rows) yo[(size_t)(nb + r) * 32 + k] = so[r * 33 + k];
  }
}

// ---- h5 = relu(u @ w2 + b2), fp32 out (feeds pooling). 64-node tile. ----
__global__ __launch_bounds__(256, 4) void k_last(const float* __restrict__ u,
                                                 const float* __restrict__ w2,
                                                 const float* __restrict__ b2,
                                                 float* __restrict__ h5) {
  __shared__ float sa[64 * 65];
  __shared__ float sb[64 * 65];
  int t = threadIdx.x;
  int nb = blockIdx.x * 64;
  int rows = min(64, N - nb);
#pragma unroll
  for (int it = 0; it < 4; ++it) {
    int idx4 = it * 256 + t;
    int r = idx4 >> 4, d4 = idx4 & 15;
    if (r < rows) {
      float4 v = ((const float4*)(u + (size_t)(nb + r) * H))[d4];
      float* dl = &sa[r * 65 + d4 * 4];
      dl[0] = v.x; dl[1] = v.y; dl[2] = v.z; dl[3] = v.w;
    }
  }
  __syncthreads();
  int l = t & 63;
  int jg = __builtin_amdgcn_readfirstlane(t >> 6);
  float h[16];
#pragma unroll
  for (int j = 0; j < 16; ++j) h[j] = b2[jg * 16 + j];
#pragma unroll 4
  for (int d = 0; d < H; ++d) {
    float v = sa[l * 65 + d];
    const float* wr = w2 + d * H + jg * 16;
#pragma unroll
    for (int j = 0; j < 16; ++j) h[j] += v * wr[j];
  }
#pragma unroll
  for (int j = 0; j < 16; ++j) sb[l * 65 + jg * 16 + j] = fmaxf(h[j], 0.f);
  __syncthreads();
#pragma unroll
  for (int it = 0; it < 16; ++it) {
    int m = it * 256 + t;
    int r = m >> 6, d = m & 63;
    if (r < rows) h5[(size_t)(nb + r) * H + d] = sb[r * 65 + d];
  }
}

__global__ void k_pool(const float* __restrict__ h, const int* __restrict__ batch,
                       float* __restrict__ g) {
  int w = (blockIdx.x * 256 + threadIdx.x) >> 6;
  int lane = threadIdx.x & 63;
  if (w >= N) return;
  int b = batch[w];
  __hip_atomic_fetch_add(&g[(size_t)b * H + lane], h[(size_t)w * H + lane],
                         __ATOMIC_RELAXED, __HIP_MEMORY_SCOPE_AGENT);
}

// out[n] = relu(g[n] @ mw1 + mb1) @ mw2 + mb2
__global__ void k_readout(const float* __restrict__ g, const float* __restrict__ mw1,
                          const float* __restrict__ mb1, const float* __restrict__ mw2,
                          const float* __restrict__ mb2, float* __restrict__ out) {
  int n = blockIdx.x * 64 + threadIdx.x;
  if (n >= G) return;
  float acc[H];
#pragma unroll
  for (int j = 0; j < H; ++j) acc[j] = mb1[j];
  const float* gr = g + (size_t)n * H;
  for (int d = 0; d < H; ++d) {
    float gd = gr[d];
    const float* wr = mw1 + d * H;
#pragma unroll
    for (int j = 0; j < H; ++j) acc[j] += gd * wr[j];
  }
#pragma unroll
  for (int j = 0; j < H; ++j) acc[j] = fmaxf(acc[j], 0.f);
  float o[OUT];
#pragma unroll
  for (int tt = 0; tt < OUT; ++tt) o[tt] = mb2[tt];
  for (int d = 0; d < H; ++d) {
    float hd = acc[d];
    const float* wr = mw2 + d * OUT;
#pragma unroll
    for (int tt = 0; tt < OUT; ++tt) o[tt] += hd * wr[tt];
  }
#pragma unroll
  for (int tt = 0; tt < OUT; ++tt) out[(size_t)n * OUT + tt] = o[tt];
}

extern "C" void kernel_launch(void* const* d_in, const int* in_sizes, int n_in,
                              void* d_out, int out_size, void* d_ws, size_t ws_size,
                              hipStream_t stream) {
  const float* x     = (const float*)d_in[0];
  const int*   ei    = (const int*)d_in[1];
  const int*   batch = (const int*)d_in[2];
  const float* w1_0  = (const float*)d_in[3];
  const float* b1_0  = (const float*)d_in[4];
  const float* w2_0  = (const float*)d_in[5];
  const float* b2_0  = (const float*)d_in[6];
  const float* w1_r  = (const float*)d_in[7];
  const float* b1_r  = (const float*)d_in[8];
  const float* w2_r  = (const float*)d_in[9];
  const float* b2_r  = (const float*)d_in[10];
  const float* mw1   = (const float*)d_in[11];
  const float* mb1   = (const float*)d_in[12];
  const float* mw2   = (const float*)d_in[13];
  const float* mb2   = (const float*)d_in[14];
  float* out = (float*)d_out;

  const int* src = ei;
  const int* dst = ei + E;

  char* ws = (char*)d_ws;
  size_t off = 0;
  auto alloc = [&](size_t bytes) -> void* {
    void* p = ws + off;
    off = (off + bytes + 255) & ~(size_t)255;
    return p;
  };
  unsigned short* ybuf = (unsigned short*)alloc((size_t)N * H * 2);  // y = h@w1, bf16
  float* ubuf = (float*)alloc((size_t)N * H * 4);                    // relu(y + Ay + b1)
  float* h5   = (float*)alloc((size_t)N * H * 4);                    // final hidden
  int* rowptr = (int*)alloc((size_t)(N + 1) * 4);
  int* cursor = (int*)alloc((size_t)N * 4);
  int* col    = (int*)alloc((size_t)E * 4);
  int* bsums  = (int*)alloc(512 * 4);
  float* gbuf = (float*)alloc((size_t)G * H * 4);

  // ---- CSR build ----
  k_zero_int<<<NB_NODES, 256, 0, stream>>>(cursor, N);
  k_hist<<<NB_EDGES, 256, 0, stream>>>(dst, cursor);
  k_scan_block<<<NB_NODES, 256, 0, stream>>>(cursor, rowptr, bsums);
  k_scan_sums<<<1, 512, 0, stream>>>(bsums, NB_NODES);
  k_scan_add<<<NB_NODES, 256, 0, stream>>>(rowptr, bsums, cursor);
  k_fill<<<NB_EDGES, 256, 0, stream>>>(src, dst, cursor, col);

  hipMemsetAsync(gbuf, 0, (size_t)G * H * 4, stream);

  // ---- layer 0: y0 = x @ w1_0 (bf16), then per-layer agg + fused MLP ----
  k_gemm_in<<<NB_TILE64, 256, 0, stream>>>(x, w1_0, ybuf);

  k_agg<<<NB_WAVENODE, 256, 0, stream>>>(ybuf, rowptr, col, b1_0, ubuf);
  k_fused<<<NB_TILE64, 256, 0, stream>>>(ubuf, w2_0, b2_0, w1_r, ybuf);

  for (int i = 0; i < 3; ++i) {
    k_agg<<<NB_WAVENODE, 256, 0, stream>>>(ybuf, rowptr, col, b1_r + i * H, ubuf);
    k_fused<<<NB_TILE64, 256, 0, stream>>>(ubuf, w2_r + i * H * H, b2_r + i * H,
                                           w1_r + (i + 1) * H * H, ybuf);
  }

  // layer 4: agg, then plain GEMM2 -> h5 (fp32)
  k_agg<<<NB_WAVENODE, 256, 0, stream>>>(ybuf, rowptr, col, b1_r + 3 * H, ubuf);
  k_last<<<NB_TILE64, 256, 0, stream>>>(ubuf, w2_r + 3 * H * H, b2_r + 3 * H, h5);

  // ---- pool + readout ----
  k_pool<<<NB_WAVENODE, 256, 0, stream>>>(h5, batch, gbuf);
  k_readout<<<8, 64, 0, stream>>>(gbuf, mw1, mb1, mw2, mb2, out);
}

// Round 4
// 774.291 us; speedup vs baseline: 2.0655x; 1.1295x over previous
//
#include <hip/hip_runtime.h>

// GIN on MI355X. Round 4:
//  - k_agg: shfl-broadcast col indices, 8 outstanding gathers, 4/2/1 tail
//  - k_fill/k_hist: 4 independent edges per thread (4 concurrent atomic chains)
//  - k_last fused with pooling (run-length segment reduce over sorted batch)
//  - cursor zeroed via hipMemsetAsync; tiled MLP kernels unchanged from r3

constexpr int N   = 100000;
constexpr int E   = 1600000;
constexpr int DIN = 128;
constexpr int H   = 64;
constexpr int OUT = 16;
constexpr int G   = 512;

constexpr int EQ = E / 4;                          // 400000
constexpr int NB_NODES    = (N + 255) / 256;       // 391
constexpr int NB_EDGE4    = (EQ + 255) / 256;      // 1563
constexpr int NB_WAVENODE = (N * 64 + 255) / 256;  // 25000 (wave per node)
constexpr int NB_TILE64   = (N + 63) / 64;         // 1563 (64-node tiles)

__device__ __forceinline__ float bf2f(unsigned short u) {
  union { unsigned int i; float f; } v;
  v.i = ((unsigned int)u) << 16;
  return v.f;
}
__device__ __forceinline__ unsigned int f2bf(float f) {
  union { float f; unsigned int i; } v;
  v.f = f;
  unsigned int r = v.i + 0x7fff + ((v.i >> 16) & 1);  // RNE
  return r >> 16;
}

// ---------------- CSR build ----------------
__global__ void k_hist(const int* __restrict__ dst, int* __restrict__ deg) {
  int e = blockIdx.x * 256 + threadIdx.x;
  if (e >= EQ) return;
  int d0 = dst[e], d1 = dst[e + EQ], d2 = dst[e + 2 * EQ], d3 = dst[e + 3 * EQ];
  atomicAdd(&deg[d0], 1);
  atomicAdd(&deg[d1], 1);
  atomicAdd(&deg[d2], 1);
  atomicAdd(&deg[d3], 1);
}

__global__ void k_scan_block(const int* __restrict__ deg, int* __restrict__ rowptr,
                             int* __restrict__ bsums) {
  __shared__ int s[256];
  int i = blockIdx.x * 256 + threadIdx.x;
  int v = (i < N) ? deg[i] : 0;
  s[threadIdx.x] = v;
  __syncthreads();
  for (int off = 1; off < 256; off <<= 1) {
    int t = 0;
    if ((int)threadIdx.x >= off) t = s[threadIdx.x - off];
    __syncthreads();
    if ((int)threadIdx.x >= off) s[threadIdx.x] += t;
    __syncthreads();
  }
  if (i < N) rowptr[i] = s[threadIdx.x] - v;
  if (threadIdx.x == 255) bsums[blockIdx.x] = s[255];
}

__global__ void k_scan_sums(int* __restrict__ bsums, int nb) {
  __shared__ int s[512];
  int t = threadIdx.x;
  int v = (t < nb) ? bsums[t] : 0;
  s[t] = v;
  __syncthreads();
  for (int off = 1; off < 512; off <<= 1) {
    int u = 0;
    if (t >= off) u = s[t - off];
    __syncthreads();
    if (t >= off) s[t] += u;
    __syncthreads();
  }
  if (t < nb) bsums[t] = s[t] - v;
}

__global__ void k_scan_add(int* __restrict__ rowptr, const int* __restrict__ bsums,
                           int* __restrict__ cursor) {
  int i = blockIdx.x * 256 + threadIdx.x;
  if (i < N) {
    int v = rowptr[i] + bsums[blockIdx.x];
    rowptr[i] = v;
    cursor[i] = v;
  }
  if (i == 0) rowptr[N] = E;
}

__global__ void k_fill(const int* __restrict__ src, const int* __restrict__ dst,
                       int* __restrict__ cursor, int* __restrict__ col) {
  int e = blockIdx.x * 256 + threadIdx.x;
  if (e >= EQ) return;
  int d0 = dst[e], d1 = dst[e + EQ], d2 = dst[e + 2 * EQ], d3 = dst[e + 3 * EQ];
  int s0 = src[e], s1 = src[e + EQ], s2 = src[e + 2 * EQ], s3 = src[e + 3 * EQ];
  int p0 = atomicAdd(&cursor[d0], 1);
  int p1 = atomicAdd(&cursor[d1], 1);
  int p2 = atomicAdd(&cursor[d2], 1);
  int p3 = atomicAdd(&cursor[d3], 1);
  col[p0] = s0;
  col[p1] = s1;
  col[p2] = s2;
  col[p3] = s3;
}

// ---- y0 = x @ w1_0 (N x 128 -> N x 64, bf16 out). 64-node tile per block. ----
__global__ __launch_bounds__(256, 4) void k_gemm_in(const float* __restrict__ x,
                                                    const float* __restrict__ w1,
                                                    unsigned short* __restrict__ y) {
  __shared__ float sx[64 * 129];
  int t = threadIdx.x;
  int nb = blockIdx.x * 64;
  int rows = min(64, N - nb);
#pragma unroll
  for (int it = 0; it < 8; ++it) {
    int idx4 = it * 256 + t;  // float4 index, 0..2047
    int r = idx4 >> 5, d4 = idx4 & 31;
    if (r < rows) {
      float4 v = ((const float4*)(x + (size_t)(nb + r) * DIN))[d4];
      float* dl = &sx[r * 129 + d4 * 4];
      dl[0] = v.x; dl[1] = v.y; dl[2] = v.z; dl[3] = v.w;
    }
  }
  __syncthreads();
  int l = t & 63;
  int jg = __builtin_amdgcn_readfirstlane(t >> 6);
  float acc[16];
#pragma unroll
  for (int j = 0; j < 16; ++j) acc[j] = 0.f;
#pragma unroll 4
  for (int d = 0; d < DIN; ++d) {
    float v = sx[l * 129 + d];
    const float* wr = w1 + d * H + jg * 16;
#pragma unroll
    for (int j = 0; j < 16; ++j) acc[j] += v * wr[j];
  }
  __syncthreads();
  unsigned int* so = (unsigned int*)sx;
#pragma unroll
  for (int k = 0; k < 8; ++k)
    so[l * 33 + jg * 8 + k] = f2bf(acc[2 * k]) | (f2bf(acc[2 * k + 1]) << 16);
  __syncthreads();
  unsigned int* yo = (unsigned int*)y;
#pragma unroll
  for (int it = 0; it < 8; ++it) {
    int m = it * 256 + t;
    int r = m >> 5, k = m & 31;
    if (r < rows) yo[(size_t)(nb + r) * 32 + k] = so[r * 33 + k];
  }
}

// ---- u = relu(y + A*y + b1); wave/node, lane/feat; 8 outstanding gathers ----
__global__ void k_agg(const unsigned short* __restrict__ y, const int* __restrict__ rowptr,
                      const int* __restrict__ col, const float* __restrict__ b1,
                      float* __restrict__ u) {
  int w = (blockIdx.x * 256 + threadIdx.x) >> 6;
  int lane = threadIdx.x & 63;
  if (w >= N) return;
  int r0 = rowptr[w], r1 = rowptr[w + 1];
  float a0 = bf2f(y[(size_t)w * H + lane]);
  float a1 = 0.f, a2 = 0.f, a3 = 0.f, a4 = 0.f, a5 = 0.f, a6 = 0.f, a7 = 0.f;
  int deg = r1 - r0;
  int kend = r0 + (deg & ~7);
  for (int k = r0; k < kend; k += 8) {
    int c = (lane < 8) ? col[k + lane] : 0;
    int c0 = __shfl(c, 0), c1 = __shfl(c, 1), c2 = __shfl(c, 2), c3 = __shfl(c, 3);
    int c4 = __shfl(c, 4), c5 = __shfl(c, 5), c6 = __shfl(c, 6), c7 = __shfl(c, 7);
    a0 += bf2f(y[(size_t)c0 * H + lane]);
    a1 += bf2f(y[(size_t)c1 * H + lane]);
    a2 += bf2f(y[(size_t)c2 * H + lane]);
    a3 += bf2f(y[(size_t)c3 * H + lane]);
    a4 += bf2f(y[(size_t)c4 * H + lane]);
    a5 += bf2f(y[(size_t)c5 * H + lane]);
    a6 += bf2f(y[(size_t)c6 * H + lane]);
    a7 += bf2f(y[(size_t)c7 * H + lane]);
  }
  int k = kend;
  if (deg & 4) {
    int c = (lane < 4) ? col[k + lane] : 0;
    int c0 = __shfl(c, 0), c1 = __shfl(c, 1), c2 = __shfl(c, 2), c3 = __shfl(c, 3);
    a0 += bf2f(y[(size_t)c0 * H + lane]);
    a1 += bf2f(y[(size_t)c1 * H + lane]);
    a2 += bf2f(y[(size_t)c2 * H + lane]);
    a3 += bf2f(y[(size_t)c3 * H + lane]);
    k += 4;
  }
  if (deg & 2) {
    int c = (lane < 2) ? col[k + lane] : 0;
    int c0 = __shfl(c, 0), c1 = __shfl(c, 1);
    a4 += bf2f(y[(size_t)c0 * H + lane]);
    a5 += bf2f(y[(size_t)c1 * H + lane]);
    k += 2;
  }
  if (deg & 1) {
    int c0 = col[k];
    a6 += bf2f(y[(size_t)c0 * H + lane]);
  }
  float r = ((a0 + a1) + (a2 + a3)) + ((a4 + a5) + (a6 + a7)) + b1[lane];
  u[(size_t)w * H + lane] = fmaxf(r, 0.f);
}

// ---- y_next = (relu(u @ w2 + b2)) @ w1next, bf16 out. 64-node tile. ----
__global__ __launch_bounds__(256, 4) void k_fused(const float* __restrict__ u,
                                                  const float* __restrict__ w2,
                                                  const float* __restrict__ b2,
                                                  const float* __restrict__ w1n,
                                                  unsigned short* __restrict__ ynext) {
  __shared__ float sa[64 * 65];
  __shared__ float sb[64 * 65];
  int t = threadIdx.x;
  int nb = blockIdx.x * 64;
  int rows = min(64, N - nb);
#pragma unroll
  for (int it = 0; it < 4; ++it) {
    int idx4 = it * 256 + t;
    int r = idx4 >> 4, d4 = idx4 & 15;
    if (r < rows) {
      float4 v = ((const float4*)(u + (size_t)(nb + r) * H))[d4];
      float* dl = &sa[r * 65 + d4 * 4];
      dl[0] = v.x; dl[1] = v.y; dl[2] = v.z; dl[3] = v.w;
    }
  }
  __syncthreads();
  int l = t & 63;
  int jg = __builtin_amdgcn_readfirstlane(t >> 6);
  float h[16];
#pragma unroll
  for (int j = 0; j < 16; ++j) h[j] = b2[jg * 16 + j];
#pragma unroll 4
  for (int d = 0; d < H; ++d) {
    float v = sa[l * 65 + d];
    const float* wr = w2 + d * H + jg * 16;
#pragma unroll
    for (int j = 0; j < 16; ++j) h[j] += v * wr[j];
  }
#pragma unroll
  for (int j = 0; j < 16; ++j) sb[l * 65 + jg * 16 + j] = fmaxf(h[j], 0.f);
  __syncthreads();
  float a[16];
#pragma unroll
  for (int j = 0; j < 16; ++j) a[j] = 0.f;
#pragma unroll 4
  for (int d = 0; d < H; ++d) {
    float v = sb[l * 65 + d];
    const float* wr = w1n + d * H + jg * 16;
#pragma unroll
    for (int j = 0; j < 16; ++j) a[j] += v * wr[j];
  }
  unsigned int* so = (unsigned int*)sa;
#pragma unroll
  for (int k = 0; k < 8; ++k)
    so[l * 33 + jg * 8 + k] = f2bf(a[2 * k]) | (f2bf(a[2 * k + 1]) << 16);
  __syncthreads();
  unsigned int* yo = (unsigned int*)ynext;
#pragma unroll
  for (int it = 0; it < 8; ++it) {
    int m = it * 256 + t;
    int r = m >> 5, k = m & 31;
    if (r < rows) yo[(size_t)(nb + r) * 32 + k] = so[r * 33 + k];
  }
}

// ---- h5 = relu(u @ w2 + b2) fused with global_add_pool into g[G][64] ----
__global__ __launch_bounds__(256, 4) void k_last_pool(const float* __restrict__ u,
                                                      const float* __restrict__ w2,
                                                      const float* __restrict__ b2,
                                                      const int* __restrict__ batch,
                                                      float* __restrict__ g) {
  __shared__ float sa[64 * 65];
  __shared__ float sb[64 * 65];
  __shared__ int sbatch[64];
  int t = threadIdx.x;
  int nb = blockIdx.x * 64;
  int rows = min(64, N - nb);
#pragma unroll
  for (int it = 0; it < 4; ++it) {
    int idx4 = it * 256 + t;
    int r = idx4 >> 4, d4 = idx4 & 15;
    if (r < rows) {
      float4 v = ((const float4*)(u + (size_t)(nb + r) * H))[d4];
      float* dl = &sa[r * 65 + d4 * 4];
      dl[0] = v.x; dl[1] = v.y; dl[2] = v.z; dl[3] = v.w;
    }
  }
  if (t < 64) sbatch[t] = batch[min(nb + t, N - 1)];
  __syncthreads();
  int l = t & 63;
  int jg = __builtin_amdgcn_readfirstlane(t >> 6);
  float h[16];
#pragma unroll
  for (int j = 0; j < 16; ++j) h[j] = b2[jg * 16 + j];
#pragma unroll 4
  for (int d = 0; d < H; ++d) {
    float v = sa[l * 65 + d];
    const float* wr = w2 + d * H + jg * 16;
#pragma unroll
    for (int j = 0; j < 16; ++j) h[j] += v * wr[j];
  }
#pragma unroll
  for (int j = 0; j < 16; ++j) sb[l * 65 + jg * 16 + j] = fmaxf(h[j], 0.f);
  __syncthreads();
  // segment-reduce 16 rows per thread along sorted batch; one atomic per run
  int d = t & 63;
  int q = t >> 6;
  int r0 = q * 16;
  int bprev = sbatch[r0];
  float acc = 0.f;
#pragma unroll 4
  for (int r = 0; r < 16; ++r) {
    int row = r0 + r;
    if (row >= rows) break;
    int b = sbatch[row];
    if (b != bprev) {
      __hip_atomic_fetch_add(&g[(size_t)bprev * H + d], acc,
                             __ATOMIC_RELAXED, __HIP_MEMORY_SCOPE_AGENT);
      acc = 0.f;
      bprev = b;
    }
    acc += sb[row * 65 + d];
  }
  if (r0 < rows)
    __hip_atomic_fetch_add(&g[(size_t)bprev * H + d], acc,
                           __ATOMIC_RELAXED, __HIP_MEMORY_SCOPE_AGENT);
}

// out[n] = relu(g[n] @ mw1 + mb1) @ mw2 + mb2
__global__ void k_readout(const float* __restrict__ g, const float* __restrict__ mw1,
                          const float* __restrict__ mb1, const float* __restrict__ mw2,
                          const float* __restrict__ mb2, float* __restrict__ out) {
  int n = blockIdx.x * 64 + threadIdx.x;
  if (n >= G) return;
  float acc[H];
#pragma unroll
  for (int j = 0; j < H; ++j) acc[j] = mb1[j];
  const float* gr = g + (size_t)n * H;
  for (int d = 0; d < H; ++d) {
    float gd = gr[d];
    const float* wr = mw1 + d * H;
#pragma unroll
    for (int j = 0; j < H; ++j) acc[j] += gd * wr[j];
  }
#pragma unroll
  for (int j = 0; j < H; ++j) acc[j] = fmaxf(acc[j], 0.f);
  float o[OUT];
#pragma unroll
  for (int tt = 0; tt < OUT; ++tt) o[tt] = mb2[tt];
  for (int d = 0; d < H; ++d) {
    float hd = acc[d];
    const float* wr = mw2 + d * OUT;
#pragma unroll
    for (int tt = 0; tt < OUT; ++tt) o[tt] += hd * wr[tt];
  }
#pragma unroll
  for (int tt = 0; tt < OUT; ++tt) out[(size_t)n * OUT + tt] = o[tt];
}

extern "C" void kernel_launch(void* const* d_in, const int* in_sizes, int n_in,
                              void* d_out, int out_size, void* d_ws, size_t ws_size,
                              hipStream_t stream) {
  const float* x     = (const float*)d_in[0];
  const int*   ei    = (const int*)d_in[1];
  const int*   batch = (const int*)d_in[2];
  const float* w1_0  = (const float*)d_in[3];
  const float* b1_0  = (const float*)d_in[4];
  const float* w2_0  = (const float*)d_in[5];
  const float* b2_0  = (const float*)d_in[6];
  const float* w1_r  = (const float*)d_in[7];
  const float* b1_r  = (const float*)d_in[8];
  const float* w2_r  = (const float*)d_in[9];
  const float* b2_r  = (const float*)d_in[10];
  const float* mw1   = (const float*)d_in[11];
  const float* mb1   = (const float*)d_in[12];
  const float* mw2   = (const float*)d_in[13];
  const float* mb2   = (const float*)d_in[14];
  float* out = (float*)d_out;

  const int* src = ei;
  const int* dst = ei + E;

  char* ws = (char*)d_ws;
  size_t off = 0;
  auto alloc = [&](size_t bytes) -> void* {
    void* p = ws + off;
    off = (off + bytes + 255) & ~(size_t)255;
    return p;
  };
  unsigned short* ybuf = (unsigned short*)alloc((size_t)N * H * 2);
  float* ubuf = (float*)alloc((size_t)N * H * 4);
  int* rowptr = (int*)alloc((size_t)(N + 1) * 4);
  int* cursor = (int*)alloc((size_t)N * 4);
  int* col    = (int*)alloc((size_t)E * 4);
  int* bsums  = (int*)alloc(512 * 4);
  float* gbuf = (float*)alloc((size_t)G * H * 4);

  // ---- CSR build ----
  hipMemsetAsync(cursor, 0, (size_t)N * 4, stream);
  k_hist<<<NB_EDGE4, 256, 0, stream>>>(dst, cursor);
  k_scan_block<<<NB_NODES, 256, 0, stream>>>(cursor, rowptr, bsums);
  k_scan_sums<<<1, 512, 0, stream>>>(bsums, NB_NODES);
  k_scan_add<<<NB_NODES, 256, 0, stream>>>(rowptr, bsums, cursor);
  k_fill<<<NB_EDGE4, 256, 0, stream>>>(src, dst, cursor, col);

  hipMemsetAsync(gbuf, 0, (size_t)G * H * 4, stream);

  // ---- layer 0 ----
  k_gemm_in<<<NB_TILE64, 256, 0, stream>>>(x, w1_0, ybuf);

  k_agg<<<NB_WAVENODE, 256, 0, stream>>>(ybuf, rowptr, col, b1_0, ubuf);
  k_fused<<<NB_TILE64, 256, 0, stream>>>(ubuf, w2_0, b2_0, w1_r, ybuf);

  for (int i = 0; i < 3; ++i) {
    k_agg<<<NB_WAVENODE, 256, 0, stream>>>(ybuf, rowptr, col, b1_r + i * H, ubuf);
    k_fused<<<NB_TILE64, 256, 0, stream>>>(ubuf, w2_r + i * H * H, b2_r + i * H,
                                           w1_r + (i + 1) * H * H, ybuf);
  }

  // layer 4: agg, then GEMM2 fused with pooling
  k_agg<<<NB_WAVENODE, 256, 0, stream>>>(ybuf, rowptr, col, b1_r + 3 * H, ubuf);
  k_last_pool<<<NB_TILE64, 256, 0, stream>>>(ubuf, w2_r + 3 * H * H, b2_r + 3 * H,
                                             batch, gbuf);

  // ---- readout ----
  k_readout<<<8, 64, 0, stream>>>(gbuf, mw1, mb1, mw2, mb2, out);
}